// Round 1
// baseline (1361.943 us; speedup 1.0000x reference)
//
#include <hip/hip_runtime.h>
#include <math.h>

#define Bn  32
#define Cn  1536
#define Tn  2048
#define BNn 128

// ---------------------------------------------------------------------------
// Kernel 1: e[b,o,t] = tanh( sum_c W_tdnn[o,c] * x[b,c,t] + b_tdnn[o] )
// Block: 256 threads computes a 128(o) x 32(t) tile for one b. K-chunk = 32.
// Thread (tid): o4 = (tid&31)*4, t4 = (tid>>5)*4 -> 4x4 micro-tile.
// ---------------------------------------------------------------------------
__global__ __launch_bounds__(256) void k_gemm1_tanh(
    const float* __restrict__ x, const float* __restrict__ W,
    const float* __restrict__ bias, float* __restrict__ e)
{
    __shared__ float sW[32][128];  // [k][o]
    __shared__ float sX[32][36];   // [k][t], pad 4 to keep float4 alignment

    const int b   = blockIdx.y;
    const int t0  = blockIdx.x * 32;
    const int tid = threadIdx.x;
    const int o4  = (tid & 31) << 2;
    const int t4  = (tid >> 5) << 2;

    const float* xb = x + (size_t)b * Cn * Tn;

    float acc00 = 0.f, acc01 = 0.f, acc02 = 0.f, acc03 = 0.f;
    float acc10 = 0.f, acc11 = 0.f, acc12 = 0.f, acc13 = 0.f;
    float acc20 = 0.f, acc21 = 0.f, acc22 = 0.f, acc23 = 0.f;
    float acc30 = 0.f, acc31 = 0.f, acc32 = 0.f, acc33 = 0.f;

    for (int k0 = 0; k0 < Cn; k0 += 32) {
        // Load W chunk: 128 o x 32 k, transpose into sW[k][o].
        {
            const int o  = tid >> 1;
            const int kk = (tid & 1) << 4;
            const float* wp = W + (size_t)o * Cn + k0 + kk;
            #pragma unroll
            for (int i = 0; i < 4; ++i) {
                float4 v = *(const float4*)(wp + 4 * i);
                sW[kk + 4*i + 0][o] = v.x;
                sW[kk + 4*i + 1][o] = v.y;
                sW[kk + 4*i + 2][o] = v.z;
                sW[kk + 4*i + 3][o] = v.w;
            }
        }
        // Load x chunk: 32 k x 32 t.
        {
            const int k  = tid >> 3;
            const int tq = (tid & 7) << 2;
            float4 v = *(const float4*)(xb + (size_t)(k0 + k) * Tn + t0 + tq);
            *(float4*)&sX[k][tq] = v;
        }
        __syncthreads();

        #pragma unroll 8
        for (int k = 0; k < 32; ++k) {
            float4 wv = *(const float4*)&sW[k][o4];
            float4 xv = *(const float4*)&sX[k][t4];
            acc00 += wv.x * xv.x; acc01 += wv.x * xv.y; acc02 += wv.x * xv.z; acc03 += wv.x * xv.w;
            acc10 += wv.y * xv.x; acc11 += wv.y * xv.y; acc12 += wv.y * xv.z; acc13 += wv.y * xv.w;
            acc20 += wv.z * xv.x; acc21 += wv.z * xv.y; acc22 += wv.z * xv.z; acc23 += wv.z * xv.w;
            acc30 += wv.w * xv.x; acc31 += wv.w * xv.y; acc32 += wv.w * xv.z; acc33 += wv.w * xv.w;
        }
        __syncthreads();
    }

    // Epilogue: bias + tanh, store float4 along t.
    const float b0 = bias[o4 + 0];
    const float b1 = bias[o4 + 1];
    const float b2 = bias[o4 + 2];
    const float b3 = bias[o4 + 3];
    float* ep = e + ((size_t)b * BNn) * Tn + t0 + t4;
    {
        float4 v = make_float4(tanhf(acc00 + b0), tanhf(acc01 + b0),
                               tanhf(acc02 + b0), tanhf(acc03 + b0));
        *(float4*)(ep + (size_t)(o4 + 0) * Tn) = v;
    }
    {
        float4 v = make_float4(tanhf(acc10 + b1), tanhf(acc11 + b1),
                               tanhf(acc12 + b1), tanhf(acc13 + b1));
        *(float4*)(ep + (size_t)(o4 + 1) * Tn) = v;
    }
    {
        float4 v = make_float4(tanhf(acc20 + b2), tanhf(acc21 + b2),
                               tanhf(acc22 + b2), tanhf(acc23 + b2));
        *(float4*)(ep + (size_t)(o4 + 2) * Tn) = v;
    }
    {
        float4 v = make_float4(tanhf(acc30 + b3), tanhf(acc31 + b3),
                               tanhf(acc32 + b3), tanhf(acc33 + b3));
        *(float4*)(ep + (size_t)(o4 + 3) * Tn) = v;
    }
}

// ---------------------------------------------------------------------------
// Kernel 2: fused a = W_attn @ e (b_attn dropped: softmax-invariant),
// masking, online softmax over T, weighted mean/std of x.
// Block: 256 threads, one b, a 64-wide c-tile, streams T in chunks of 32.
// Thread: cl = tid>>2 (c row), tt = tid&3 (covers 8 t values each chunk).
// ---------------------------------------------------------------------------
__global__ __launch_bounds__(256) void k_attn_stats(
    const float* __restrict__ x, const float* __restrict__ e,
    const float* __restrict__ Wa, const int* __restrict__ mask,
    float* __restrict__ out)
{
    __shared__ float sWa[64][132];  // [c][k], stride 132 -> 2-way max bank alias
    __shared__ float sE[128][36];   // [k][t]
    __shared__ float sX[64][36];    // [c][t]
    __shared__ int   sM[32];

    const int b   = blockIdx.y;
    const int c0  = blockIdx.x * 64;
    const int tid = threadIdx.x;
    const int cl  = tid >> 2;  // 0..63
    const int tt  = tid & 3;   // 0..3

    // Load W_attn tile once: rows c0..c0+63, 128 floats each.
    {
        const int row = tid >> 2;
        const int seg = (tid & 3) * 32;
        const float* wp = Wa + (size_t)(c0 + row) * BNn + seg;
        #pragma unroll
        for (int i = 0; i < 8; ++i)
            *(float4*)&sWa[row][seg + 4*i] = *(const float4*)(wp + 4*i);
    }

    const float* eb = e + (size_t)b * BNn * Tn;
    const float* xb = x + (size_t)b * Cn * Tn + (size_t)c0 * Tn;
    const int*   mb = mask + (size_t)b * Tn;

    float m_run = -1e9f;
    float S0 = 0.f, S1 = 0.f, S2 = 0.f;

    for (int t0 = 0; t0 < Tn; t0 += 32) {
        // Stage e chunk (128 x 32), x chunk (64 x 32), mask chunk (32).
        {
            const int row = tid >> 1;
            const int seg = (tid & 1) * 16;
            const float* ep = eb + (size_t)row * Tn + t0 + seg;
            #pragma unroll
            for (int i = 0; i < 4; ++i)
                *(float4*)&sE[row][seg + 4*i] = *(const float4*)(ep + 4*i);
        }
        {
            const int row = tid >> 2;
            const int seg = (tid & 3) * 8;
            const float* xp = xb + (size_t)row * Tn + t0 + seg;
            *(float4*)&sX[row][seg]     = *(const float4*)(xp);
            *(float4*)&sX[row][seg + 4] = *(const float4*)(xp + 4);
        }
        if (tid < 32) sM[tid] = mb[t0 + tid];
        __syncthreads();

        // a[j] for c = c0+cl, t = t0 + tt*8 + j
        float a0=0.f,a1=0.f,a2=0.f,a3=0.f,a4=0.f,a5=0.f,a6=0.f,a7=0.f;
        #pragma unroll 8
        for (int k = 0; k < BNn; ++k) {
            const float w  = sWa[cl][k];
            float4 e0 = *(const float4*)&sE[k][tt * 8];
            float4 e1 = *(const float4*)&sE[k][tt * 8 + 4];
            a0 += w * e0.x; a1 += w * e0.y; a2 += w * e0.z; a3 += w * e0.w;
            a4 += w * e1.x; a5 += w * e1.y; a6 += w * e1.z; a7 += w * e1.w;
        }
        float a[8] = {a0,a1,a2,a3,a4,a5,a6,a7};
        #pragma unroll
        for (int j = 0; j < 8; ++j)
            if (sM[tt * 8 + j]) a[j] = -1e9f;

        // chunk max over this thread's 8 + the 4-lane group
        float mx = a[0];
        #pragma unroll
        for (int j = 1; j < 8; ++j) mx = fmaxf(mx, a[j]);
        mx = fmaxf(mx, __shfl_xor(mx, 1));
        mx = fmaxf(mx, __shfl_xor(mx, 2));

        const float m_new = fmaxf(m_run, mx);
        const float scale = __expf(m_run - m_new);
        float p0 = 0.f, p1 = 0.f, p2 = 0.f;
        #pragma unroll
        for (int j = 0; j < 8; ++j) {
            const float p  = __expf(a[j] - m_new);
            const float xv = sX[cl][tt * 8 + j];
            p0 += p;
            p1 += p * xv;
            p2 += p * xv * xv;
        }
        S0 = S0 * scale + p0;
        S1 = S1 * scale + p1;
        S2 = S2 * scale + p2;
        m_run = m_new;
        __syncthreads();
    }

    // Reduce S0,S1,S2 across the 4-lane group (m_run identical across group).
    S0 += __shfl_xor(S0, 1); S0 += __shfl_xor(S0, 2);
    S1 += __shfl_xor(S1, 1); S1 += __shfl_xor(S1, 2);
    S2 += __shfl_xor(S2, 1); S2 += __shfl_xor(S2, 2);

    if (tt == 0) {
        const float mean = S1 / S0;
        float var = S2 / S0 - mean * mean;
        var = fmaxf(var, 1e-9f);
        out[(size_t)b * (2 * Cn) + c0 + cl]      = mean;
        out[(size_t)b * (2 * Cn) + Cn + c0 + cl] = sqrtf(var);
    }
}

extern "C" void kernel_launch(void* const* d_in, const int* in_sizes, int n_in,
                              void* d_out, int out_size, void* d_ws, size_t ws_size,
                              hipStream_t stream) {
    const float* x      = (const float*)d_in[0];
    const int*   mask   = (const int*)d_in[1];
    const float* W_tdnn = (const float*)d_in[2];
    const float* b_tdnn = (const float*)d_in[3];
    const float* W_attn = (const float*)d_in[4];
    // d_in[5] = b_attn: constant over t per row -> cancels in softmax. Unused.
    float* out = (float*)d_out;
    float* e   = (float*)d_ws;  // (B, BN, T) fp32 = 33.55 MB

    dim3 g1(Tn / 32, Bn);
    k_gemm1_tanh<<<g1, 256, 0, stream>>>(x, W_tdnn, b_tdnn, e);

    dim3 g2(Cn / 64, Bn);
    k_attn_stats<<<g2, 256, 0, stream>>>(x, e, W_attn, mask, out);
}

// Round 2
// 705.679 us; speedup vs baseline: 1.9300x; 1.9300x over previous
//
#include <hip/hip_runtime.h>
#include <math.h>

#define Bn  32
#define Cn  1536
#define Tn  2048
#define BNn 128

typedef __attribute__((ext_vector_type(8))) short bf16x8;
typedef __attribute__((ext_vector_type(4))) float fx4;

// round-to-nearest-even fp32 -> bf16 (as ushort)
__device__ __forceinline__ unsigned int f2bf1(float f) {
    unsigned int u = __float_as_uint(f);
    return (u + 0x7fffu + ((u >> 16) & 1u)) >> 16;
}
__device__ __forceinline__ float fast_tanh(float v) {
    // 1 - 2/(e^{2v}+1); exact at +-inf saturation, ~1e-6 rel err
    return 1.f - 2.f / (__expf(2.f * v) + 1.f);
}

// ---------------------------------------------------------------------------
// Prep: convert W_tdnn (BN x C) and W_attn (C x BN) fp32 -> bf16.
// Both have BN*C = 196608 elements.
// ---------------------------------------------------------------------------
__global__ void k_prep(const float* __restrict__ W1f, const float* __restrict__ Waf,
                       short* __restrict__ W1b, short* __restrict__ Wab) {
    int i = blockIdx.x * 256 + threadIdx.x;
    if (i < BNn * Cn) {
        W1b[i] = (short)f2bf1(W1f[i]);
        Wab[i] = (short)f2bf1(Waf[i]);
    }
}

// ---------------------------------------------------------------------------
// GEMM1: e[b][t][o] = tanh( sum_c x[b][c][t] * W[o][c] + bias[o] )   (e^T layout!)
// MFMA 16x16x32 bf16, D[m=t][n=o]. Per-block tile: 128 t x 128 o, K-chunk 64.
// A (x^T) staged to LDS with 16B-block XOR swizzle; B (W bf16) direct from L2.
// Grid: (T/128, B), 256 threads (4 waves, 2x2 over 64t x 64o).
// ---------------------------------------------------------------------------
__global__ __launch_bounds__(256, 2) void k_gemm1(
    const float* __restrict__ x, const short* __restrict__ W1,
    const float* __restrict__ bias, short* __restrict__ e)
{
    __shared__ short sA[128 * 64];  // [t][k] bf16, 16B blocks swizzled by ^(t&7)

    const int b    = blockIdx.y;
    const int t0   = blockIdx.x * 128;
    const int tid  = threadIdx.x;
    const int lane = tid & 63;
    const int wv   = tid >> 6;
    const int ln   = lane & 15;   // MFMA m/n within tile
    const int g    = lane >> 4;   // MFMA k-group / row-group
    const int wt   = (wv & 1) * 64;
    const int wo   = (wv >> 1) * 64;

    const float* xb = x + (size_t)b * Cn * Tn + t0;

    const int t4 = (tid & 31) * 4;       // t quad this thread stages
    const int cq = (tid >> 5) * 4;       // c quad base (0..28)

    fx4 acc[4][4];
    #pragma unroll
    for (int i = 0; i < 4; ++i)
        #pragma unroll
        for (int j = 0; j < 4; ++j) acc[i][j] = (fx4){0.f, 0.f, 0.f, 0.f};

    for (int k0 = 0; k0 < Cn; k0 += 64) {
        // B frags straight from global bf16 W (L2-resident, 393 KB total)
        bf16x8 bfr[4][2];
        #pragma unroll
        for (int nn = 0; nn < 4; ++nn)
            #pragma unroll
            for (int kt = 0; kt < 2; ++kt)
                bfr[nn][kt] = *(const bf16x8*)(W1 + (size_t)(wo + nn * 16 + ln) * Cn
                                               + k0 + kt * 32 + g * 8);

        // x chunk: 64c x 128t fp32, coalesced float4 along t
        float4 xr[2][4];
        #pragma unroll
        for (int p = 0; p < 2; ++p) {
            const int c = cq + p * 32;
            #pragma unroll
            for (int j = 0; j < 4; ++j)
                xr[p][j] = *(const float4*)(xb + (size_t)(k0 + c + j) * Tn + t4);
        }
        __syncthreads();   // previous chunk's frag reads done
        // transpose-in-register: pack 4 c's per t, swizzled b64 LDS writes
        #pragma unroll
        for (int p = 0; p < 2; ++p) {
            const int c   = cq + p * 32;
            const int blk = c >> 3;
            const int sub = c & 7;  // 0 or 4
            #pragma unroll
            for (int i = 0; i < 4; ++i) {
                const int t = t4 + i;
                unsigned int lo = f2bf1(((const float*)&xr[p][0])[i]) |
                                  (f2bf1(((const float*)&xr[p][1])[i]) << 16);
                unsigned int hi = f2bf1(((const float*)&xr[p][2])[i]) |
                                  (f2bf1(((const float*)&xr[p][3])[i]) << 16);
                const int idx = t * 64 + ((blk ^ (t & 7)) << 3) + sub;
                *(uint2*)(sA + idx) = make_uint2(lo, hi);
            }
        }
        __syncthreads();

        #pragma unroll
        for (int kt = 0; kt < 2; ++kt) {
            bf16x8 af[4];
            #pragma unroll
            for (int mm = 0; mm < 4; ++mm) {
                const int t = wt + mm * 16 + ln;
                af[mm] = *(const bf16x8*)(sA + t * 64 + (((kt * 4 + g) ^ (t & 7)) << 3));
            }
            #pragma unroll
            for (int mm = 0; mm < 4; ++mm)
                #pragma unroll
                for (int nn = 0; nn < 4; ++nn)
                    acc[mm][nn] = __builtin_amdgcn_mfma_f32_16x16x32_bf16(
                        af[mm], bfr[nn][kt], acc[mm][nn], 0, 0, 0);
        }
    }

    // Epilogue: bias + tanh, bf16 store to e[b][t][o] (o contiguous)
    float bs[4];
    #pragma unroll
    for (int nn = 0; nn < 4; ++nn) bs[nn] = bias[wo + nn * 16 + ln];

    short* eb = e + ((size_t)b * Tn + t0 + wt) * BNn + wo;
    #pragma unroll
    for (int mm = 0; mm < 4; ++mm)
        #pragma unroll
        for (int nn = 0; nn < 4; ++nn) {
            #pragma unroll
            for (int r = 0; r < 4; ++r) {
                const int t = mm * 16 + g * 4 + r;   // D row = (lane>>4)*4 + reg
                const float v = fast_tanh(acc[mm][nn][r] + bs[nn]);
                eb[(size_t)t * BNn + nn * 16 + ln] = (short)f2bf1(v);
            }
        }
}

// ---------------------------------------------------------------------------
// Kernel 2: a = Wa_bf16 @ e^T (MFMA, K=128), mask, per-lane online softmax,
// weighted mean/std of fp32 x. Block = 128 thr (2 waves), c-tile 64
// (wave handles 32 c), streams T in chunks of 64.
// ---------------------------------------------------------------------------
__global__ __launch_bounds__(128, 2) void k_attn2(
    const float* __restrict__ x, const short* __restrict__ e,
    const short* __restrict__ Wab, const int* __restrict__ mask,
    float* __restrict__ out)
{
    __shared__ short sE[64 * 128];  // [t][k] bf16, 16B blocks swizzled by ^(t&15)

    const int b    = blockIdx.y;
    const int c0   = blockIdx.x * 64;
    const int tid  = threadIdx.x;
    const int lane = tid & 63;
    const int wv   = tid >> 6;
    const int ln   = lane & 15;
    const int g    = lane >> 4;
    const int cw   = c0 + wv * 32;

    const float* xb    = x + (size_t)b * Cn * Tn;
    const short* ebase = e + (size_t)b * Tn * BNn;
    const int*   mb    = mask + (size_t)b * Tn;

    // A frags (Wa rows, K=128) resident in registers for the whole kernel
    bf16x8 af[2][4];
    #pragma unroll
    for (int mt = 0; mt < 2; ++mt)
        #pragma unroll
        for (int kt = 0; kt < 4; ++kt)
            af[mt][kt] = *(const bf16x8*)(Wab + (size_t)(cw + mt * 16 + ln) * BNn
                                          + kt * 32 + g * 8);

    // online-softmax state: 8 c's per lane (mt*4 + r)
    float mS[8], S0[8], S1[8], S2[8];
    #pragma unroll
    for (int s = 0; s < 8; ++s) { mS[s] = -1e30f; S0[s] = 0.f; S1[s] = 0.f; S2[s] = 0.f; }

    for (int t0 = 0; t0 < Tn; t0 += 64) {
        // prefetch x (this lane's 8 c-rows x 4 t's) and mask
        float xv[2][4][4];
        #pragma unroll
        for (int mt = 0; mt < 2; ++mt)
            #pragma unroll
            for (int r = 0; r < 4; ++r) {
                const float* xr = xb + (size_t)(cw + mt * 16 + g * 4 + r) * Tn + t0 + ln;
                #pragma unroll
                for (int nt = 0; nt < 4; ++nt) xv[mt][r][nt] = xr[nt * 16];
            }
        int mv4[4];
        #pragma unroll
        for (int nt = 0; nt < 4; ++nt) mv4[nt] = mb[t0 + nt * 16 + ln];

        // e chunk 64t x 128k -> regs (swizzled source so LDS writes are linear)
        uint4 ev[8];
        #pragma unroll
        for (int j = 0; j < 8; ++j) {
            const int p   = j * 128 + tid;
            const int t   = p >> 4;
            const int blk = (tid & 15) ^ (t & 15);
            ev[j] = *(const uint4*)(ebase + (size_t)(t0 + t) * BNn + blk * 8);
        }
        __syncthreads();   // prev chunk's frag reads done
        #pragma unroll
        for (int j = 0; j < 8; ++j)
            *(uint4*)(sE + (size_t)(j * 128 + tid) * 8) = ev[j];
        __syncthreads();

        fx4 acc[2][4];
        #pragma unroll
        for (int mt = 0; mt < 2; ++mt)
            #pragma unroll
            for (int nt = 0; nt < 4; ++nt) acc[mt][nt] = (fx4){0.f, 0.f, 0.f, 0.f};

        #pragma unroll
        for (int kt = 0; kt < 4; ++kt) {
            bf16x8 bfr[4];
            #pragma unroll
            for (int nt = 0; nt < 4; ++nt) {
                const int t = nt * 16 + ln;
                bfr[nt] = *(const bf16x8*)(sE + t * 128 + (((kt * 4 + g) ^ (t & 15)) << 3));
            }
            #pragma unroll
            for (int mt = 0; mt < 2; ++mt)
                #pragma unroll
                for (int nt = 0; nt < 4; ++nt)
                    acc[mt][nt] = __builtin_amdgcn_mfma_f32_16x16x32_bf16(
                        af[mt][kt], bfr[nt], acc[mt][nt], 0, 0, 0);
        }

        // online softmax + stats update (per lane, no cross-lane in loop)
        #pragma unroll
        for (int mt = 0; mt < 2; ++mt)
            #pragma unroll
            for (int r = 0; r < 4; ++r) {
                const int s = mt * 4 + r;
                float a0 = mv4[0] ? -1e9f : acc[mt][0][r];
                float a1 = mv4[1] ? -1e9f : acc[mt][1][r];
                float a2 = mv4[2] ? -1e9f : acc[mt][2][r];
                float a3 = mv4[3] ? -1e9f : acc[mt][3][r];
                const float mc = fmaxf(fmaxf(a0, a1), fmaxf(a2, a3));
                const float mn = fmaxf(mS[s], mc);
                const float sc = __expf(mS[s] - mn);
                const float p0 = __expf(a0 - mn), p1 = __expf(a1 - mn);
                const float p2 = __expf(a2 - mn), p3 = __expf(a3 - mn);
                const float x0 = xv[mt][r][0], x1 = xv[mt][r][1];
                const float x2 = xv[mt][r][2], x3 = xv[mt][r][3];
                S0[s] = S0[s] * sc + (p0 + p1 + p2 + p3);
                S1[s] = S1[s] * sc + (p0 * x0 + p1 * x1 + p2 * x2 + p3 * x3);
                S2[s] = S2[s] * sc + (p0 * x0 * x0 + p1 * x1 * x1 + p2 * x2 * x2 + p3 * x3 * x3);
                mS[s] = mn;
            }
    }

    // merge the 16 t-partitions (lanes with same g) with max-rescaling
    #pragma unroll
    for (int s = 0; s < 8; ++s) {
        float m = mS[s], s0 = S0[s], s1 = S1[s], s2 = S2[s];
        #pragma unroll
        for (int off = 1; off < 16; off <<= 1) {
            const float mo = __shfl_xor(m, off);
            const float q0 = __shfl_xor(s0, off);
            const float q1 = __shfl_xor(s1, off);
            const float q2 = __shfl_xor(s2, off);
            const float mn = fmaxf(m, mo);
            const float ea = __expf(m - mn), eb2 = __expf(mo - mn);
            s0 = s0 * ea + q0 * eb2;
            s1 = s1 * ea + q1 * eb2;
            s2 = s2 * ea + q2 * eb2;
            m = mn;
        }
        if (ln == 0) {
            const int c = cw + (s >> 2) * 16 + g * 4 + (s & 3);
            const float mean = s1 / s0;
            const float var  = fmaxf(s2 / s0 - mean * mean, 1e-9f);
            out[(size_t)b * (2 * Cn) + c]      = mean;
            out[(size_t)b * (2 * Cn) + Cn + c] = sqrtf(var);
        }
    }
}

extern "C" void kernel_launch(void* const* d_in, const int* in_sizes, int n_in,
                              void* d_out, int out_size, void* d_ws, size_t ws_size,
                              hipStream_t stream) {
    const float* x      = (const float*)d_in[0];
    const int*   mask   = (const int*)d_in[1];
    const float* W_tdnn = (const float*)d_in[2];
    const float* b_tdnn = (const float*)d_in[3];
    const float* W_attn = (const float*)d_in[4];
    // d_in[5] = b_attn: constant over t per row -> cancels in softmax. Unused.
    float* out = (float*)d_out;

    short* e_bf = (short*)d_ws;                                        // B*T*BN bf16 = 16.78 MB
    short* W1b  = (short*)((char*)d_ws + (size_t)Bn * Tn * BNn * 2);   // BN*C bf16
    short* Wab  = W1b + (size_t)BNn * Cn;                              // C*BN bf16

    k_prep<<<dim3((BNn * Cn + 255) / 256), 256, 0, stream>>>(W_tdnn, W_attn, W1b, Wab);
    k_gemm1<<<dim3(Tn / 128, Bn), 256, 0, stream>>>(x, W1b, b_tdnn, e_bf);
    k_attn2<<<dim3(Cn / 64, Bn), 128, 0, stream>>>(x, e_bf, Wab, mask, out);
}